// Round 10
// baseline (255.045 us; speedup 1.0000x reference)
//
#include <hip/hip_runtime.h>
#include <hip/hip_bf16.h>

typedef __attribute__((ext_vector_type(8))) short s16x8;
typedef __attribute__((ext_vector_type(4))) float f32x4;

#define D_FEAT 512
#define SLICES 8
#define SLICE_D 64

__device__ __forceinline__ unsigned short f2bf(float f) {
  __hip_bfloat16 h = __float2bfloat16(f);
  return *reinterpret_cast<unsigned short*>(&h);
}

__device__ __forceinline__ float bitsf(unsigned int u) {
  union { unsigned int i; float f; } c;
  c.i = u;
  return c.f;
}

// ---------------- zero scratch ----------------

__global__ __launch_bounds__(256) void zero_k(int4* __restrict__ p, int n16) {
  int i = blockIdx.x * 256 + threadIdx.x;
  if (i < n16) p[i] = make_int4(0, 0, 0, 0);
}

// ---------------- fused: histogram (deg) + x -> bf16 slice-major convert ----------------

__global__ __launch_bounds__(256) void hx_k(const int* __restrict__ dst, int E,
                                            int* __restrict__ deg,
                                            const float* __restrict__ x,
                                            unsigned short* __restrict__ xs, int n8, int hb,
                                            int Nn) {
  int bid = blockIdx.x;
  if (bid < hb) {
    int i = bid * 256 + threadIdx.x;
    if (i < E) atomicAdd(&deg[dst[i]], 1);
  } else {
    int i = (bid - hb) * 256 + threadIdx.x;
    if (i < n8) {
      int n = i >> 6;
      int c = i & 63;
      int s = c >> 3;
      int off = (c & 7);
      const float4* p = (const float4*)x + (size_t)i * 2;
      float4 u = p[0], v = p[1];
      s16x8 r;
      r[0] = (short)f2bf(u.x); r[1] = (short)f2bf(u.y);
      r[2] = (short)f2bf(u.z); r[3] = (short)f2bf(u.w);
      r[4] = (short)f2bf(v.x); r[5] = (short)f2bf(v.y);
      r[6] = (short)f2bf(v.z); r[7] = (short)f2bf(v.w);
      ((s16x8*)xs)[((size_t)s * Nn + n) * 8 + off] = r;
    }
  }
}

// ---------------- scan (rowstart) + degree-bucketed node order ----------------

__global__ __launch_bounds__(1024) void scan_k(const int* __restrict__ deg,
                                               int* __restrict__ rowstart,
                                               unsigned short* __restrict__ nodeord, int n) {
  __shared__ int wsum[16];
  __shared__ int carry_s;
  __shared__ int hist[65];
  int tid = threadIdx.x;
  int lane = tid & 63, wid = tid >> 6;
  if (tid == 0) carry_s = 0;
  __syncthreads();
  for (int t0 = 0; t0 < n; t0 += 1024) {
    int i = t0 + tid;
    int v = (i < n) ? deg[i] : 0;
    int s = v;
#pragma unroll
    for (int off = 1; off < 64; off <<= 1) {
      int t = __shfl_up(s, off);
      if (lane >= off) s += t;
    }
    if (lane == 63) wsum[wid] = s;
    __syncthreads();
    if (wid == 0) {
      int ws = (lane < 16) ? wsum[lane] : 0;
#pragma unroll
      for (int off = 1; off < 16; off <<= 1) {
        int t = __shfl_up(ws, off);
        if (lane >= off) ws += t;
      }
      if (lane < 16) wsum[lane] = ws;
    }
    __syncthreads();
    int carry = carry_s;
    int wbase = (wid > 0) ? wsum[wid - 1] : 0;
    if (i < n) rowstart[i] = carry + wbase + s - v;
    int total = wsum[15];
    __syncthreads();
    if (tid == 0) carry_s = carry + total;
    __syncthreads();
  }
  if (tid == 0) rowstart[n] = carry_s;
  if (tid < 65) hist[tid] = 0;
  __syncthreads();
  for (int i = tid; i < n; i += 1024) atomicAdd(&hist[min(deg[i], 64)], 1);
  __syncthreads();
  if (tid == 0) {
    int run = 0;
    for (int b = 0; b < 65; ++b) { int c = hist[b]; hist[b] = run; run += c; }
  }
  __syncthreads();
  for (int i = tid; i < n; i += 1024) {
    int b = min(deg[i], 64);
    int pos = atomicAdd(&hist[b], 1);
    nodeord[pos] = (unsigned short)i;
  }
}

__global__ void fill_k(const int* __restrict__ src, const int* __restrict__ dst, int E,
                       const int* __restrict__ rowstart, int* __restrict__ cursor,
                       unsigned short* __restrict__ ep16) {
  int i = blockIdx.x * 256 + threadIdx.x;
  if (i < E) {
    int d = dst[i];
    int pos = atomicAdd(&cursor[d], 1);
    ep16[rowstart[d] + pos] = (unsigned short)src[i];
  }
}

// ---------------- slice-per-XCD aggregation, ILP-8 ----------------

__global__ __launch_bounds__(256, 6) void agg_k(const unsigned short* __restrict__ xs,
                                                const int* __restrict__ rowstart,
                                                const unsigned short* __restrict__ ep16,
                                                const unsigned short* __restrict__ nodeord,
                                                unsigned short* __restrict__ h, int Nn) {
  int slice = blockIdx.x & 7;
  int nb = blockIdx.x >> 3;
  int wid = threadIdx.x >> 6, lane = threadIdx.x & 63;
  int g = lane >> 3, sub = lane & 7;
  int slot = (nb * 4 + wid) * 8 + g;
  int node = nodeord[slot];
  int beg = rowstart[node];
  int deg = rowstart[node + 1] - beg;
  int degm1 = max(deg - 1, 0);
  int dm = deg;
  dm = max(dm, __shfl_xor(dm, 8));
  dm = max(dm, __shfl_xor(dm, 16));
  dm = max(dm, __shfl_xor(dm, 32));
  const s16x8* sb = (const s16x8*)xs + (size_t)slice * Nn * 8;
  s16x8 own = sb[node * 8 + sub];
  float2 acc[4];
#pragma unroll
  for (int q = 0; q < 4; ++q) {
    unsigned int d = (unsigned int)((const int*)&own)[q];
    acc[q].x = bitsf(d << 16);
    acc[q].y = bitsf(d & 0xffff0000u);
  }
  for (int t = 0; t < dm; t += 8) {
    s16x8 v[8];
    float m[8];
#pragma unroll
    for (int b = 0; b < 8; ++b) {
      int tt = t + b;
      int e = ep16[beg + min(tt, degm1)];
      m[b] = (tt < deg) ? 1.f : 0.f;
      v[b] = sb[e * 8 + sub];
    }
#pragma unroll
    for (int b = 0; b < 8; ++b) {
#pragma unroll
      for (int q = 0; q < 4; ++q) {
        unsigned int d = (unsigned int)((const int*)&v[b])[q];
        acc[q].x = fmaf(m[b], bitsf(d << 16), acc[q].x);
        acc[q].y = fmaf(m[b], bitsf(d & 0xffff0000u), acc[q].y);
      }
    }
  }
  s16x8 r;
#pragma unroll
  for (int q = 0; q < 4; ++q) {
    r[q * 2 + 0] = (short)f2bf(acc[q].x);
    r[q * 2 + 1] = (short)f2bf(acc[q].y);
  }
  __builtin_nontemporal_store(r, (s16x8*)(h + (size_t)node * D_FEAT + slice * SLICE_D + sub * 8));
}

// ---------------- weights: Wt[n][k] = bf16(W[k][n]), LDS-tiled transpose ----------------

__global__ __launch_bounds__(256) void wconv_k(const float* __restrict__ W1,
                                               const float* __restrict__ W2,
                                               unsigned short* __restrict__ W1t,
                                               unsigned short* __restrict__ W2t) {
  __shared__ float tile[64][65];
  int t = blockIdx.x;
  const float* W = W1;
  unsigned short* Wt = W1t;
  if (t >= 64) { t -= 64; W = W2; Wt = W2t; }
  int tr = (t >> 3) * 64;
  int tc = (t & 7) * 64;
  int tid = threadIdx.x;
  int c4 = (tid & 15) * 4, rg = tid >> 4;
#pragma unroll
  for (int rr = 0; rr < 64; rr += 16) {
    int r = rr + rg;
    float4 vv = *(const float4*)&W[(size_t)(tr + r) * 512 + tc + c4];
    tile[r][c4] = vv.x; tile[r][c4 + 1] = vv.y; tile[r][c4 + 2] = vv.z; tile[r][c4 + 3] = vv.w;
  }
  __syncthreads();
  int ch = tid & 15;
#pragma unroll
  for (int rr = 0; rr < 64; rr += 16) {
    int n = rr + rg;
    int k0 = ch * 4;
    ushort4 o;
    o.x = f2bf(tile[k0 + 0][n]);
    o.y = f2bf(tile[k0 + 1][n]);
    o.z = f2bf(tile[k0 + 2][n]);
    o.w = f2bf(tile[k0 + 3][n]);
    *(ushort4*)&Wt[(size_t)(tc + n) * 512 + tr + k0] = o;
  }
}

// ---------------- GEMM v3: NO LDS, NO BARRIERS ----------------
// B (0.5MB) is L2-resident on every XCD; A is streamed once (L2-shared by the
// 4 tn-blocks on the same XCD). Both operands are loaded straight from global
// in the MFMA fragment pattern (wave = 16 rows x 64B contiguous lines).
// K-loop register-double-buffered with named arrays (compile-time indices).
// ~12 resident waves/CU drift freely -> L2 latency hidden by ILP + TLP.

template <int RELU, int OUTBF16>
__global__ __launch_bounds__(256) void gemm_k(const unsigned short* __restrict__ A,
                                              const unsigned short* __restrict__ Bt,
                                              const float* __restrict__ bias,
                                              void* __restrict__ Cout, int M) {
  const int K = 512;
  int mt = (M + 127) >> 7;
  int qx = (mt + 7) >> 3;
  int b = blockIdx.x;
  int x = b & 7, i = b >> 3;
  int tm = x * qx + (i >> 2);
  int tn = i & 3;
  if (tm >= mt) return;
  int tid = threadIdx.x;
  int wave = tid >> 6, lane = tid & 63;
  int lr = lane & 15, lh = lane >> 4;
  int wm = (wave >> 1) * 64, wn = (wave & 1) * 64;

  const unsigned short* arow[4];
  const unsigned short* brow[4];
#pragma unroll
  for (int m = 0; m < 4; ++m) {
    int r = tm * 128 + wm + m * 16 + lr;
    if (r > M - 1) r = M - 1;
    arow[m] = A + (size_t)r * K + lh * 8;
  }
#pragma unroll
  for (int n = 0; n < 4; ++n) {
    int r = tn * 128 + wn + n * 16 + lr;
    brow[n] = Bt + (size_t)r * K + lh * 8;
  }

  f32x4 zero = {0.f, 0.f, 0.f, 0.f};
  f32x4 acc[4][4];
#pragma unroll
  for (int m = 0; m < 4; ++m)
#pragma unroll
    for (int n = 0; n < 4; ++n) acc[m][n] = zero;

  s16x8 avA[4], bvA[4], avB[4], bvB[4];
#define LOADF(av, bv, t)                                   \
  _Pragma("unroll") for (int m = 0; m < 4; ++m)            \
      av[m] = *(const s16x8*)(arow[m] + (t) * 32);         \
  _Pragma("unroll") for (int n = 0; n < 4; ++n)            \
      bv[n] = *(const s16x8*)(brow[n] + (t) * 32);
#define MFMAS(av, bv)                                      \
  _Pragma("unroll") for (int m = 0; m < 4; ++m)            \
  _Pragma("unroll") for (int n = 0; n < 4; ++n)            \
      acc[m][n] = __builtin_amdgcn_mfma_f32_16x16x32_bf16(av[m], bv[n], acc[m][n], 0, 0, 0);

  LOADF(avA, bvA, 0)
#pragma unroll
  for (int t = 0; t < 16; t += 2) {
    if (t + 1 < 16) { LOADF(avB, bvB, t + 1) }
    MFMAS(avA, bvA)
    if (t + 2 < 16) { LOADF(avA, bvA, t + 2) }
    MFMAS(avB, bvB)
  }
#undef LOADF
#undef MFMAS

  // epilogue: C/D layout col=lane&15, row=(lane>>4)*4+j  [measured m89]
#pragma unroll
  for (int n = 0; n < 4; ++n) {
    int col = tn * 128 + wn + n * 16 + lr;
    float bval = bias[col];
#pragma unroll
    for (int m = 0; m < 4; ++m) {
#pragma unroll
      for (int j = 0; j < 4; ++j) {
        int row = tm * 128 + wm + m * 16 + lh * 4 + j;
        if (row < M) {
          float v = acc[m][n][j] + bval;
          if (RELU) v = fmaxf(v, 0.f);
          if (OUTBF16)
            ((unsigned short*)Cout)[(size_t)row * 512 + col] = f2bf(v);
          else
            ((float*)Cout)[(size_t)row * 512 + col] = v;
        }
      }
    }
  }
}

// ---------------- launch ----------------

extern "C" void kernel_launch(void* const* d_in, const int* in_sizes, int n_in,
                              void* d_out, int out_size, void* d_ws, size_t ws_size,
                              hipStream_t stream) {
  const float* x = (const float*)d_in[0];
  const int* ei = (const int*)d_in[1];
  const float* W1 = (const float*)d_in[2];
  const float* b1 = (const float*)d_in[3];
  const float* W2 = (const float*)d_in[4];
  const float* b2 = (const float*)d_in[5];
  const int N = in_sizes[0] / D_FEAT;  // 20000
  const int E = in_sizes[1] / 2;       // 640000
  const int* src = ei;
  const int* dst = ei + E;

  char* w = (char*)d_ws;
  auto alloc = [&](size_t bytes) {
    void* p = (void*)w;
    w += (bytes + 255) & ~(size_t)255;
    return p;
  };
  unsigned short* ep16 = (unsigned short*)alloc((size_t)E * 2 + 256);
  int* deg = (int*)alloc((size_t)N * 4);
  int* cursor = (int*)alloc((size_t)N * 4);
  int* rowstart = (int*)alloc((size_t)(N + 1) * 4);
  unsigned short* nodeord = (unsigned short*)alloc((size_t)N * 2);
  unsigned short* W1t = (unsigned short*)alloc((size_t)512 * 512 * 2);
  unsigned short* W2t = (unsigned short*)alloc((size_t)512 * 512 * 2);
  unsigned short* c1 = (unsigned short*)alloc((size_t)N * 512 * 2);
  unsigned short* h = (unsigned short*)d_out;
  unsigned short* xs = (unsigned short*)d_out + (size_t)N * D_FEAT;

  size_t zbytes = (size_t)((char*)cursor - (char*)deg) + (size_t)N * 4;
  int zn16 = (int)(zbytes / 16);
  zero_k<<<(zn16 + 255) / 256, 256, 0, stream>>>((int4*)deg, zn16);
  int hb = (E + 255) / 256;
  int n8 = N * D_FEAT / 8;
  int xbk = (n8 + 255) / 256;
  hx_k<<<hb + xbk, 256, 0, stream>>>(dst, E, deg, x, xs, n8, hb, N);
  scan_k<<<1, 1024, 0, stream>>>(deg, rowstart, nodeord, N);
  fill_k<<<hb, 256, 0, stream>>>(src, dst, E, rowstart, cursor, ep16);
  wconv_k<<<128, 256, 0, stream>>>(W1, W2, W1t, W2t);
  agg_k<<<8 * (N / 32), 256, 0, stream>>>(xs, rowstart, ep16, nodeord, h, N);
  int mt = (N + 127) / 128, qx = (mt + 7) / 8;
  int grid = 8 * qx * 4;
  gemm_k<1, 1><<<grid, 256, 0, stream>>>(h, W1t, b1, c1, N);
  gemm_k<0, 0><<<grid, 256, 0, stream>>>(c1, W2t, b2, d_out, N);
}

// Round 11
// 208.912 us; speedup vs baseline: 1.2208x; 1.2208x over previous
//
#include <hip/hip_runtime.h>
#include <hip/hip_bf16.h>

typedef __attribute__((ext_vector_type(8))) short s16x8;
typedef __attribute__((ext_vector_type(4))) float f32x4;

#define D_FEAT 512
#define SLICES 8
#define SLICE_D 64

__device__ __forceinline__ unsigned short f2bf(float f) {
  __hip_bfloat16 h = __float2bfloat16(f);
  return *reinterpret_cast<unsigned short*>(&h);
}

__device__ __forceinline__ float bitsf(unsigned int u) {
  union { unsigned int i; float f; } c;
  c.i = u;
  return c.f;
}

__device__ __forceinline__ void async16(void* lds, const void* g) {
  __builtin_amdgcn_global_load_lds(
      (const __attribute__((address_space(1))) void*)g,
      (__attribute__((address_space(3))) void*)lds, 16, 0, 0);
}

// ---------------- zero scratch ----------------

__global__ __launch_bounds__(256) void zero_k(int4* __restrict__ p, int n16) {
  int i = blockIdx.x * 256 + threadIdx.x;
  if (i < n16) p[i] = make_int4(0, 0, 0, 0);
}

// ---------------- fused: histogram (deg) + x -> bf16 slice-major convert ----------------

__global__ __launch_bounds__(256) void hx_k(const int* __restrict__ dst, int E,
                                            int* __restrict__ deg,
                                            const float* __restrict__ x,
                                            unsigned short* __restrict__ xs, int n8, int hb,
                                            int Nn) {
  int bid = blockIdx.x;
  if (bid < hb) {
    int i = bid * 256 + threadIdx.x;
    if (i < E) atomicAdd(&deg[dst[i]], 1);
  } else {
    int i = (bid - hb) * 256 + threadIdx.x;
    if (i < n8) {
      int n = i >> 6;
      int c = i & 63;
      int s = c >> 3;
      int off = (c & 7);
      const float4* p = (const float4*)x + (size_t)i * 2;
      float4 u = p[0], v = p[1];
      s16x8 r;
      r[0] = (short)f2bf(u.x); r[1] = (short)f2bf(u.y);
      r[2] = (short)f2bf(u.z); r[3] = (short)f2bf(u.w);
      r[4] = (short)f2bf(v.x); r[5] = (short)f2bf(v.y);
      r[6] = (short)f2bf(v.z); r[7] = (short)f2bf(v.w);
      ((s16x8*)xs)[((size_t)s * Nn + n) * 8 + off] = r;
    }
  }
}

// ---------------- scan (rowstart) + degree-bucketed node order ----------------

__global__ __launch_bounds__(1024) void scan_k(const int* __restrict__ deg,
                                               int* __restrict__ rowstart,
                                               unsigned short* __restrict__ nodeord, int n) {
  __shared__ int wsum[16];
  __shared__ int carry_s;
  __shared__ int hist[65];
  int tid = threadIdx.x;
  int lane = tid & 63, wid = tid >> 6;
  if (tid == 0) carry_s = 0;
  __syncthreads();
  for (int t0 = 0; t0 < n; t0 += 1024) {
    int i = t0 + tid;
    int v = (i < n) ? deg[i] : 0;
    int s = v;
#pragma unroll
    for (int off = 1; off < 64; off <<= 1) {
      int t = __shfl_up(s, off);
      if (lane >= off) s += t;
    }
    if (lane == 63) wsum[wid] = s;
    __syncthreads();
    if (wid == 0) {
      int ws = (lane < 16) ? wsum[lane] : 0;
#pragma unroll
      for (int off = 1; off < 16; off <<= 1) {
        int t = __shfl_up(ws, off);
        if (lane >= off) ws += t;
      }
      if (lane < 16) wsum[lane] = ws;
    }
    __syncthreads();
    int carry = carry_s;
    int wbase = (wid > 0) ? wsum[wid - 1] : 0;
    if (i < n) rowstart[i] = carry + wbase + s - v;
    int total = wsum[15];
    __syncthreads();
    if (tid == 0) carry_s = carry + total;
    __syncthreads();
  }
  if (tid == 0) rowstart[n] = carry_s;
  if (tid < 65) hist[tid] = 0;
  __syncthreads();
  for (int i = tid; i < n; i += 1024) atomicAdd(&hist[min(deg[i], 64)], 1);
  __syncthreads();
  if (tid == 0) {
    int run = 0;
    for (int b = 0; b < 65; ++b) { int c = hist[b]; hist[b] = run; run += c; }
  }
  __syncthreads();
  for (int i = tid; i < n; i += 1024) {
    int b = min(deg[i], 64);
    int pos = atomicAdd(&hist[b], 1);
    nodeord[pos] = (unsigned short)i;
  }
}

__global__ void fill_k(const int* __restrict__ src, const int* __restrict__ dst, int E,
                       const int* __restrict__ rowstart, int* __restrict__ cursor,
                       unsigned short* __restrict__ ep16) {
  int i = blockIdx.x * 256 + threadIdx.x;
  if (i < E) {
    int d = dst[i];
    int pos = atomicAdd(&cursor[d], 1);
    ep16[rowstart[d] + pos] = (unsigned short)src[i];
  }
}

// ---------------- slice-per-XCD aggregation, ILP-8 ----------------

__global__ __launch_bounds__(256, 6) void agg_k(const unsigned short* __restrict__ xs,
                                                const int* __restrict__ rowstart,
                                                const unsigned short* __restrict__ ep16,
                                                const unsigned short* __restrict__ nodeord,
                                                unsigned short* __restrict__ h, int Nn) {
  int slice = blockIdx.x & 7;
  int nb = blockIdx.x >> 3;
  int wid = threadIdx.x >> 6, lane = threadIdx.x & 63;
  int g = lane >> 3, sub = lane & 7;
  int slot = (nb * 4 + wid) * 8 + g;
  int node = nodeord[slot];
  int beg = rowstart[node];
  int deg = rowstart[node + 1] - beg;
  int degm1 = max(deg - 1, 0);
  int dm = deg;
  dm = max(dm, __shfl_xor(dm, 8));
  dm = max(dm, __shfl_xor(dm, 16));
  dm = max(dm, __shfl_xor(dm, 32));
  const s16x8* sb = (const s16x8*)xs + (size_t)slice * Nn * 8;
  s16x8 own = sb[node * 8 + sub];
  float2 acc[4];
#pragma unroll
  for (int q = 0; q < 4; ++q) {
    unsigned int d = (unsigned int)((const int*)&own)[q];
    acc[q].x = bitsf(d << 16);
    acc[q].y = bitsf(d & 0xffff0000u);
  }
  for (int t = 0; t < dm; t += 8) {
    s16x8 v[8];
    float m[8];
#pragma unroll
    for (int b = 0; b < 8; ++b) {
      int tt = t + b;
      int e = ep16[beg + min(tt, degm1)];
      m[b] = (tt < deg) ? 1.f : 0.f;
      v[b] = sb[e * 8 + sub];
    }
#pragma unroll
    for (int b = 0; b < 8; ++b) {
#pragma unroll
      for (int q = 0; q < 4; ++q) {
        unsigned int d = (unsigned int)((const int*)&v[b])[q];
        acc[q].x = fmaf(m[b], bitsf(d << 16), acc[q].x);
        acc[q].y = fmaf(m[b], bitsf(d & 0xffff0000u), acc[q].y);
      }
    }
  }
  s16x8 r;
#pragma unroll
  for (int q = 0; q < 4; ++q) {
    r[q * 2 + 0] = (short)f2bf(acc[q].x);
    r[q * 2 + 1] = (short)f2bf(acc[q].y);
  }
  __builtin_nontemporal_store(r, (s16x8*)(h + (size_t)node * D_FEAT + slice * SLICE_D + sub * 8));
}

// ---------------- weights: Wt[n][k] = bf16(W[k][n]), LDS-tiled transpose ----------------

__global__ __launch_bounds__(256) void wconv_k(const float* __restrict__ W1,
                                               const float* __restrict__ W2,
                                               unsigned short* __restrict__ W1t,
                                               unsigned short* __restrict__ W2t) {
  __shared__ float tile[64][65];
  int t = blockIdx.x;
  const float* W = W1;
  unsigned short* Wt = W1t;
  if (t >= 64) { t -= 64; W = W2; Wt = W2t; }
  int tr = (t >> 3) * 64;
  int tc = (t & 7) * 64;
  int tid = threadIdx.x;
  int c4 = (tid & 15) * 4, rg = tid >> 4;
#pragma unroll
  for (int rr = 0; rr < 64; rr += 16) {
    int r = rr + rg;
    float4 vv = *(const float4*)&W[(size_t)(tr + r) * 512 + tc + c4];
    tile[r][c4] = vv.x; tile[r][c4 + 1] = vv.y; tile[r][c4 + 2] = vv.z; tile[r][c4 + 3] = vv.w;
  }
  __syncthreads();
  int ch = tid & 15;
#pragma unroll
  for (int rr = 0; rr < 64; rr += 16) {
    int n = rr + rg;
    int k0 = ch * 4;
    ushort4 o;
    o.x = f2bf(tile[k0 + 0][n]);
    o.y = f2bf(tile[k0 + 1][n]);
    o.z = f2bf(tile[k0 + 2][n]);
    o.w = f2bf(tile[k0 + 3][n]);
    *(ushort4*)&Wt[(size_t)(tc + n) * 512 + tr + k0] = o;
  }
}

// ---------------- GEMM v4: 64x128 tile, BK=32, triple-buffered LDS, depth-2 ----------------
// Smaller tile -> grid 1252 active blocks (~4.9/CU, 4 resident via 36KB LDS)
// -> 16 waves/CU of INDEPENDENT blocks drift across barriers and cover each
// other's vmcnt stalls (R10 lesson: TLP, not per-wave ILP, is the lever).
// Counted vmcnt(3) (3 async-loads/wave/stage), never 0 until the last step.

template <int RELU, int OUTBF16>
__global__ __launch_bounds__(256, 4) void gemm_k(const unsigned short* __restrict__ A,
                                                 const unsigned short* __restrict__ Bt,
                                                 const float* __restrict__ bias,
                                                 void* __restrict__ Cout, int M) {
  const int K = 512;
  const int NSTEP = 16;  // K / 32
  __shared__ unsigned short As[3][64 * 32];
  __shared__ unsigned short Bs[3][128 * 32];
  int mt = (M + 63) >> 6;
  int qx = (mt + 7) >> 3;  // M-panels per XCD
  int b = blockIdx.x;
  int x = b & 7, i = b >> 3;
  int tm = x * qx + (i >> 2);
  int tn = i & 3;
  if (tm >= mt) return;
  int tid = threadIdx.x;
  int wave = tid >> 6, lane = tid & 63;
  int lr = lane & 15, lh = lane >> 4;
  int p3 = lr & 3;  // row&3 for all fragment rows this lane reads
  int wm = (wave >> 1) * 32, wn = (wave & 1) * 64;

  // stage one 64x32 A-tile (256 chunks) + 128x32 B-tile (512 chunks).
  // 3 async16/wave. LDS dest is wave-uniform base; HW adds lane*16.
  auto stage = [&](int pb, int k0) {
    {
      int cb = wave * 64 + lane;
      int row = cb >> 2;
      int cg = (cb & 3) ^ (row & 3);  // inverse-swizzled global chunk
      int ga = tm * 64 + row;
      if (ga > M - 1) ga = M - 1;
      async16(&As[pb][(size_t)(wave * 64) * 8], A + (size_t)ga * K + k0 + cg * 8);
    }
#pragma unroll
    for (int ii = 0; ii < 2; ++ii) {
      int cb = ii * 256 + wave * 64 + lane;
      int row = cb >> 2;
      int cg = (cb & 3) ^ (row & 3);
      int gb = tn * 128 + row;
      async16(&Bs[pb][(size_t)(ii * 256 + wave * 64) * 8], Bt + (size_t)gb * K + k0 + cg * 8);
    }
  };

  f32x4 zero = {0.f, 0.f, 0.f, 0.f};
  f32x4 acc[2][4];
#pragma unroll
  for (int m = 0; m < 2; ++m)
#pragma unroll
    for (int n = 0; n < 4; ++n) acc[m][n] = zero;

  stage(0, 0);
  stage(1, 32);

#pragma unroll
  for (int t = 0; t < NSTEP; ++t) {
    int pb = t % 3;
    if (t < NSTEP - 1)
      asm volatile("s_waitcnt vmcnt(3)" ::: "memory");  // tile t landed; t+1 in flight
    else
      asm volatile("s_waitcnt vmcnt(0)" ::: "memory");
    __builtin_amdgcn_s_barrier();
    s16x8 av[2], bv[4];
#pragma unroll
    for (int m = 0; m < 2; ++m) {
      int r = wm + m * 16 + lr;
      av[m] = *(const s16x8*)&As[pb][r * 32 + (lh ^ p3) * 8];
    }
#pragma unroll
    for (int n = 0; n < 4; ++n) {
      int r = wn + n * 16 + lr;
      bv[n] = *(const s16x8*)&Bs[pb][r * 32 + (lh ^ p3) * 8];
    }
#pragma unroll
    for (int m = 0; m < 2; ++m)
#pragma unroll
      for (int n = 0; n < 4; ++n)
        acc[m][n] = __builtin_amdgcn_mfma_f32_16x16x32_bf16(av[m], bv[n], acc[m][n], 0, 0, 0);
    __builtin_amdgcn_s_barrier();
    if (t + 2 < NSTEP) stage((t + 2) % 3, (t + 2) * 32);
  }

  // epilogue: C/D layout col=lane&15, row=(lane>>4)*4+j  [measured m89]
#pragma unroll
  for (int n = 0; n < 4; ++n) {
    int col = tn * 128 + wn + n * 16 + lr;
    float bval = bias[col];
#pragma unroll
    for (int m = 0; m < 2; ++m) {
#pragma unroll
      for (int j = 0; j < 4; ++j) {
        int row = tm * 64 + wm + m * 16 + lh * 4 + j;
        if (row < M) {
          float v = acc[m][n][j] + bval;
          if (RELU) v = fmaxf(v, 0.f);
          if (OUTBF16)
            ((unsigned short*)Cout)[(size_t)row * 512 + col] = f2bf(v);
          else
            ((float*)Cout)[(size_t)row * 512 + col] = v;
        }
      }
    }
  }
}

// ---------------- launch ----------------

extern "C" void kernel_launch(void* const* d_in, const int* in_sizes, int n_in,
                              void* d_out, int out_size, void* d_ws, size_t ws_size,
                              hipStream_t stream) {
  const float* x = (const float*)d_in[0];
  const int* ei = (const int*)d_in[1];
  const float* W1 = (const float*)d_in[2];
  const float* b1 = (const float*)d_in[3];
  const float* W2 = (const float*)d_in[4];
  const float* b2 = (const float*)d_in[5];
  const int N = in_sizes[0] / D_FEAT;  // 20000
  const int E = in_sizes[1] / 2;       // 640000
  const int* src = ei;
  const int* dst = ei + E;

  char* w = (char*)d_ws;
  auto alloc = [&](size_t bytes) {
    void* p = (void*)w;
    w += (bytes + 255) & ~(size_t)255;
    return p;
  };
  unsigned short* ep16 = (unsigned short*)alloc((size_t)E * 2 + 256);
  int* deg = (int*)alloc((size_t)N * 4);
  int* cursor = (int*)alloc((size_t)N * 4);
  int* rowstart = (int*)alloc((size_t)(N + 1) * 4);
  unsigned short* nodeord = (unsigned short*)alloc((size_t)N * 2);
  unsigned short* W1t = (unsigned short*)alloc((size_t)512 * 512 * 2);
  unsigned short* W2t = (unsigned short*)alloc((size_t)512 * 512 * 2);
  unsigned short* c1 = (unsigned short*)alloc((size_t)N * 512 * 2);
  unsigned short* h = (unsigned short*)d_out;
  unsigned short* xs = (unsigned short*)d_out + (size_t)N * D_FEAT;

  size_t zbytes = (size_t)((char*)cursor - (char*)deg) + (size_t)N * 4;
  int zn16 = (int)(zbytes / 16);
  zero_k<<<(zn16 + 255) / 256, 256, 0, stream>>>((int4*)deg, zn16);
  int hb = (E + 255) / 256;
  int n8 = N * D_FEAT / 8;
  int xbk = (n8 + 255) / 256;
  hx_k<<<hb + xbk, 256, 0, stream>>>(dst, E, deg, x, xs, n8, hb, N);
  scan_k<<<1, 1024, 0, stream>>>(deg, rowstart, nodeord, N);
  fill_k<<<hb, 256, 0, stream>>>(src, dst, E, rowstart, cursor, ep16);
  wconv_k<<<128, 256, 0, stream>>>(W1, W2, W1t, W2t);
  agg_k<<<8 * (N / 32), 256, 0, stream>>>(xs, rowstart, ep16, nodeord, h, N);
  int mt = (N + 63) / 64, qx = (mt + 7) / 8;
  int grid = 8 * qx * 4;
  gemm_k<1, 1><<<grid, 256, 0, stream>>>(h, W1t, b1, c1, N);
  gemm_k<0, 0><<<grid, 256, 0, stream>>>(c1, W2t, b2, d_out, N);
}